// Round 1
// baseline (258.895 us; speedup 1.0000x reference)
//
#include <hip/hip_runtime.h>

#define T_MAX 11  // MAX_TURNS from the reference

// ---------------------------------------------------------------------------
// Kernel 1 (tiny, 1 block): compute segment offsets, masked logits via
// wave dot-products, softmax -> probs (written straight to d_out tail),
// and per-row weights w[r] -> workspace.
// ---------------------------------------------------------------------------
__global__ __launch_bounds__(256) void k_probs(
    const float* __restrict__ hist,       // [rows, hidden]
    const float* __restrict__ W,          // [hidden]
    const float* __restrict__ b,          // [1]
    const int*   __restrict__ slice_mask, // [>=S]
    int S, int rows, int hidden,
    float* __restrict__ probs_out,        // [S, T_MAX]
    float* __restrict__ w_out,            // [rows]
    int*   __restrict__ ns_out,           // [S]
    int*   __restrict__ off_out)          // [S]
{
    __shared__ int   s_ns[64];
    __shared__ int   s_off[64];
    __shared__ float s_exp[64 * T_MAX];

    const int tid = threadIdx.x;

    if (tid == 0) {
        int acc = 0;
        for (int s = 0; s < S; ++s) {
            s_ns[s]  = slice_mask[s];
            s_off[s] = acc;
            acc += s_ns[s];
        }
    }
    __syncthreads();

    const int lane   = tid & 63;
    const int wave   = tid >> 6;
    const int nwaves = blockDim.x >> 6;
    const float bias = b[0];

    // one wave per (s,t) pair
    for (int p = wave; p < S * T_MAX; p += nwaves) {
        const int s   = p / T_MAX;
        const int t   = p - s * T_MAX;
        const int pad = T_MAX - s_ns[s];
        float e = 0.0f;
        if (t >= pad) {
            int idx = s_off[s] + t - pad;
            idx = max(0, min(idx, rows - 1));
            const float* hrow = hist + (size_t)idx * hidden;
            float acc = 0.0f;
            for (int h = lane; h < hidden; h += 64)
                acc += hrow[h] * W[h];
            // 64-lane butterfly reduce
            #pragma unroll
            for (int d = 32; d > 0; d >>= 1)
                acc += __shfl_down(acc, d);
            acc = __shfl(acc, 0);
            e = expf(acc + bias);   // reference does plain exp (no max-sub)
        }
        if (lane == 0) s_exp[p] = e;
    }
    __syncthreads();

    // per-slice softmax normalization + write probs
    if (tid < S) {
        float sum = 0.0f;
        for (int t = 0; t < T_MAX; ++t) sum += s_exp[tid * T_MAX + t];
        const float inv = 1.0f / sum;
        for (int t = 0; t < T_MAX; ++t) {
            const float pr = s_exp[tid * T_MAX + t] * inv;
            s_exp[tid * T_MAX + t] = pr;
            probs_out[tid * T_MAX + t] = pr;
        }
        ns_out[tid]  = s_ns[tid];
        off_out[tid] = s_off[tid];
    }
    __syncthreads();

    // per-row weight w[r] = probs[seg(r), pad(seg)+pos]
    if (tid < rows) {
        int seg = 0;
        while (seg < S - 1 && tid >= s_off[seg] + s_ns[seg]) ++seg;
        const int pos = tid - s_off[seg];
        const int tt  = (T_MAX - s_ns[seg]) + pos;
        w_out[tid] = s_exp[seg * T_MAX + tt];
    }
}

// ---------------------------------------------------------------------------
// Kernel 2 (bulk, memory-bound): weighted segment sums, float4-vectorized.
//   out_bert[s, c] = sum_k w[off[s]+k] * bert[off[s]+k, c],   c < seq*hidden/4
//   out_mtl [s, c] = sum_k w[off[s]+k] * mtl [off[s]+k, c],   c < hidden/4
// mtl columns are appended after all bert columns in the flat index space.
// ---------------------------------------------------------------------------
__global__ __launch_bounds__(256) void k_segsum(
    const float4* __restrict__ bert,
    const float4* __restrict__ mtl,
    const float*  __restrict__ w,
    const int*    __restrict__ ns,
    const int*    __restrict__ off,
    int S, int bert_cols4, int mtl_cols4,
    float4* __restrict__ out_bert,
    float4* __restrict__ out_mtl)
{
    const long i = (long)blockIdx.x * blockDim.x + threadIdx.x;
    const long bert_total = (long)S * bert_cols4;

    if (i < bert_total) {
        const int s = (int)(i / bert_cols4);
        const long c = i - (long)s * bert_cols4;
        const int o = off[s], n = ns[s];
        float4 acc = {0.f, 0.f, 0.f, 0.f};
        for (int k = 0; k < n; ++k) {
            const float wk = w[o + k];
            const float4 v = bert[(long)(o + k) * bert_cols4 + c];
            acc.x += wk * v.x; acc.y += wk * v.y;
            acc.z += wk * v.z; acc.w += wk * v.w;
        }
        out_bert[i] = acc;
    } else {
        const long j = i - bert_total;
        if (j < (long)S * mtl_cols4) {
            const int s = (int)(j / mtl_cols4);
            const long c = j - (long)s * mtl_cols4;
            const int o = off[s], n = ns[s];
            float4 acc = {0.f, 0.f, 0.f, 0.f};
            for (int k = 0; k < n; ++k) {
                const float wk = w[o + k];
                const float4 v = mtl[(long)(o + k) * mtl_cols4 + c];
                acc.x += wk * v.x; acc.y += wk * v.y;
                acc.z += wk * v.z; acc.w += wk * v.w;
            }
            out_mtl[j] = acc;
        }
    }
}

extern "C" void kernel_launch(void* const* d_in, const int* in_sizes, int n_in,
                              void* d_out, int out_size, void* d_ws, size_t ws_size,
                              hipStream_t stream) {
    const float* bert = (const float*)d_in[0];
    const float* hist = (const float*)d_in[1];
    const float* mtl  = (const float*)d_in[2];
    const float* W    = (const float*)d_in[3];
    const float* b    = (const float*)d_in[4];
    const int* slice_mask = (const int*)d_in[5];

    const int hidden = in_sizes[3];                       // 768
    const int rows   = in_sizes[1] / hidden;              // 64
    const int seq    = in_sizes[0] / (rows * hidden);     // 512
    // out layout: [S,seq,hidden] + [S,hidden] + [S,T_MAX]  (flat, in order)
    const int S = out_size / (seq * hidden + hidden + T_MAX);   // 16

    float* out       = (float*)d_out;
    float* out_bert  = out;
    float* out_mtl   = out_bert + (size_t)S * seq * hidden;
    float* out_probs = out_mtl  + (size_t)S * hidden;

    // workspace: w[rows] floats, then (256B-aligned) ns[S], off[S] ints
    float* w_ws  = (float*)d_ws;
    char*  base  = (char*)d_ws;
    size_t ofs   = (((size_t)rows * sizeof(float)) + 255) & ~(size_t)255;
    int*   ns_ws  = (int*)(base + ofs);
    int*   off_ws = ns_ws + S;

    k_probs<<<1, 256, 0, stream>>>(hist, W, b, slice_mask, S, rows, hidden,
                                   out_probs, w_ws, ns_ws, off_ws);

    const int bert_cols4 = seq * hidden / 4;
    const int mtl_cols4  = hidden / 4;
    const long total = (long)S * (bert_cols4 + mtl_cols4);
    const int blocks = (int)((total + 255) / 256);

    k_segsum<<<blocks, 256, 0, stream>>>((const float4*)bert, (const float4*)mtl,
                                         w_ws, ns_ws, off_ws,
                                         S, bert_cols4, mtl_cols4,
                                         (float4*)out_bert, (float4*)out_mtl);
}

// Round 2
// 172.646 us; speedup vs baseline: 1.4996x; 1.4996x over previous
//
#include <hip/hip_runtime.h>
#include <math.h>

#define T_MAX 11  // MAX_TURNS from the reference

// ---------------------------------------------------------------------------
// Fully fused kernel. Grid = S segments x nchunks chunks.
// Each block:
//   1. computes its segment's (off, n) from slice_mask (thread 0),
//   2. computes the n <= T_MAX valid logits (one wave per valid row; invalid
//      turns have exp*valid == 0 so they never enter the softmax sum),
//   3. normalizes to weights in LDS,
//   4. (chunk 0 only) writes the probs row incl. zero padding,
//   5. grid-strides its chunk of the weighted segment-sum over bert + mtl.
// Redundant per-block dot recompute is ~12 KB of L2-resident reads — cheap,
// and it removes the 100 us latency-bound single-block k_probs entirely.
// ---------------------------------------------------------------------------
__global__ __launch_bounds__(256) void k_fused(
    const float4* __restrict__ bert,      // [rows, bert_cols4] (f4)
    const float4* __restrict__ mtl,       // [rows, mtl_cols4] (f4)
    const float*  __restrict__ hist,      // [rows, hidden]
    const float*  __restrict__ W,         // [hidden]
    const float*  __restrict__ b,         // [1]
    const int*    __restrict__ slice_mask,
    int S, int hidden,
    int bert_cols4, int mtl_cols4,
    int nchunks, int chunk_f4,
    float4* __restrict__ out_bert,        // [S, bert_cols4]
    float4* __restrict__ out_mtl,         // [S, mtl_cols4]
    float*  __restrict__ out_probs)       // [S, T_MAX]
{
    __shared__ float s_exp[T_MAX];
    __shared__ float s_wk[T_MAX];
    __shared__ int   s_off, s_n;

    const int sidx  = blockIdx.x / nchunks;
    const int chunk = blockIdx.x - sidx * nchunks;
    const int tid  = threadIdx.x;
    const int lane = tid & 63;
    const int wave = tid >> 6;

    if (tid == 0) {
        int acc = 0, n = 0;
        for (int i = 0; i < S; ++i) {
            const int v = slice_mask[i];
            if (i < sidx) acc += v;
            if (i == sidx) n = v;
        }
        s_off = acc;
        s_n   = n;
    }
    __syncthreads();

    const int o = s_off;
    const int n = s_n;

    // one wave per valid row's dot product
    for (int k = wave; k < n; k += 4) {
        const float* hrow = hist + (size_t)(o + k) * hidden;
        float acc = 0.0f;
        for (int h = lane; h < hidden; h += 64)
            acc += hrow[h] * W[h];
        #pragma unroll
        for (int d = 32; d > 0; d >>= 1)
            acc += __shfl_down(acc, d);
        if (lane == 0) s_exp[k] = expf(acc + b[0]);
    }
    __syncthreads();

    if (tid == 0) {
        float sum = 0.0f;
        for (int k = 0; k < n; ++k) sum += s_exp[k];
        const float inv = 1.0f / sum;
        for (int k = 0; k < n; ++k) s_wk[k] = s_exp[k] * inv;
    }
    __syncthreads();

    if (chunk == 0 && tid < T_MAX) {
        const int pad = T_MAX - n;
        out_probs[sidx * T_MAX + tid] = (tid >= pad) ? s_wk[tid - pad] : 0.0f;
    }

    // weighted segment sum over this block's chunk of columns
    const int total_f4 = bert_cols4 + mtl_cols4;
    const int lo = chunk * chunk_f4;
    const int hi = min(lo + chunk_f4, total_f4);

    for (int i = lo + tid; i < hi; i += 256) {
        float4 acc = {0.f, 0.f, 0.f, 0.f};
        if (i < bert_cols4) {
            const float4* p = bert + (size_t)o * bert_cols4 + i;
            for (int k = 0; k < n; ++k) {
                const float wk = s_wk[k];
                const float4 v = p[(size_t)k * bert_cols4];
                acc.x += wk * v.x; acc.y += wk * v.y;
                acc.z += wk * v.z; acc.w += wk * v.w;
            }
            out_bert[(size_t)sidx * bert_cols4 + i] = acc;
        } else {
            const int j = i - bert_cols4;
            const float4* p = mtl + (size_t)o * mtl_cols4 + j;
            for (int k = 0; k < n; ++k) {
                const float wk = s_wk[k];
                const float4 v = p[(size_t)k * mtl_cols4];
                acc.x += wk * v.x; acc.y += wk * v.y;
                acc.z += wk * v.z; acc.w += wk * v.w;
            }
            out_mtl[(size_t)sidx * mtl_cols4 + j] = acc;
        }
    }
}

extern "C" void kernel_launch(void* const* d_in, const int* in_sizes, int n_in,
                              void* d_out, int out_size, void* d_ws, size_t ws_size,
                              hipStream_t stream) {
    const float* bert = (const float*)d_in[0];
    const float* hist = (const float*)d_in[1];
    const float* mtl  = (const float*)d_in[2];
    const float* W    = (const float*)d_in[3];
    const float* b    = (const float*)d_in[4];
    const int* slice_mask = (const int*)d_in[5];

    const int hidden = in_sizes[3];                       // 768
    const int rows   = in_sizes[1] / hidden;              // 64
    const int seq    = in_sizes[0] / (rows * hidden);     // 512
    const int S = out_size / (seq * hidden + hidden + T_MAX);   // 16

    float* out       = (float*)d_out;
    float* out_bert  = out;
    float* out_mtl   = out_bert + (size_t)S * seq * hidden;
    float* out_probs = out_mtl  + (size_t)S * hidden;

    const int bert_cols4 = seq * hidden / 4;   // 98304
    const int mtl_cols4  = hidden / 4;         // 192
    const int total_f4   = bert_cols4 + mtl_cols4;

    const int chunk_f4 = 2048;                 // 8 f4 per thread per chunk
    const int nchunks  = (total_f4 + chunk_f4 - 1) / chunk_f4;   // 49
    const int grid     = S * nchunks;          // 784 blocks -> all co-resident

    k_fused<<<grid, 256, 0, stream>>>((const float4*)bert, (const float4*)mtl,
                                      hist, W, b, slice_mask,
                                      S, hidden, bert_cols4, mtl_cols4,
                                      nchunks, chunk_f4,
                                      (float4*)out_bert, (float4*)out_mtl,
                                      out_probs);
}